// Round 1
// baseline (1477.945 us; speedup 1.0000x reference)
//
#include <hip/hip_runtime.h>

#define EPS 1e-5f

// ---------------------------------------------------------------------------
// Edge-index dtype detection: JAX may emit int32 (x64 disabled) or int64.
// For int64 little-endian, the high word of every index is 0 (values < 2^31).
// Sample 16 high-word positions; all-zero => int64.
__global__ void k_detect(const int* __restrict__ ei, int* __restrict__ flag) {
    if (blockIdx.x == 0 && threadIdx.x == 0) {
        int is64 = 1;
        for (int k = 0; k < 16; ++k) is64 &= (ei[2 * k + 1] == 0) ? 1 : 0;
        *flag = is64;
    }
}

__device__ __forceinline__ void load_edge(const int* __restrict__ ei, int E, int e,
                                          int f, int& s, int& d) {
    if (f) { s = ei[2 * e]; d = ei[2 * E + 2 * e]; }
    else   { s = ei[e];     d = ei[E + e]; }
}

// ---------------------------------------------------------------------------
// Layer-1 scatter: agg1[dst] += x[src] (2 channels), deg[dst] += 1
__global__ void k_scatter1(const float* __restrict__ x, const int* __restrict__ ei,
                           const int* __restrict__ flag, int E,
                           float* __restrict__ agg1, float* __restrict__ deg) {
    int e = blockIdx.x * blockDim.x + threadIdx.x;
    if (e >= E) return;
    int f = *flag, s, d;
    load_edge(ei, E, e, f, s, d);
    atomicAdd(&agg1[2 * d],     x[2 * s]);
    atomicAdd(&agg1[2 * d + 1], x[2 * s + 1]);
    atomicAdd(&deg[d], 1.0f);
}

__global__ void k_invdeg(float* __restrict__ deg, int n) {
    int i = blockIdx.x * blockDim.x + threadIdx.x;
    if (i < n) deg[i] = 1.0f / fmaxf(deg[i], 1.0f);
}

// ---------------------------------------------------------------------------
// Layer-1 dense: h1[i,c] = (agg1[i,:]*inv)@W1l + b1 + x[i,:]@W1r, plus BN stats.
// Block = 256 threads = 4 waves; lane c = channel, wave = node within group.
__global__ __launch_bounds__(256) void k_dense1(
    const float* __restrict__ x, const float* __restrict__ agg1,
    const float* __restrict__ invd,
    const float* __restrict__ W1l, const float* __restrict__ b1,
    const float* __restrict__ W1r,
    float* __restrict__ h1, float* __restrict__ stats, int n) {
    int tid = threadIdx.x, c = tid & 63, w = tid >> 6;
    float wl0 = W1l[c], wl1 = W1l[64 + c];
    float wr0 = W1r[c], wr1 = W1r[64 + c];
    float bb = b1[c];
    float ls = 0.f, lq = 0.f;
    for (int i = blockIdx.x * 4 + w; i < n; i += gridDim.x * 4) {
        float inv = invd[i];
        float a0 = agg1[2 * i] * inv, a1 = agg1[2 * i + 1] * inv;
        float x0 = x[2 * i], x1v = x[2 * i + 1];
        float h = fmaf(a0, wl0, fmaf(a1, wl1, fmaf(x0, wr0, fmaf(x1v, wr1, bb))));
        h1[(long long)i * 64 + c] = h;
        ls += h; lq += h * h;
    }
    __shared__ float red[256];
    red[tid] = ls; __syncthreads();
    if (tid < 64) atomicAdd(&stats[tid], red[tid] + red[tid + 64] + red[tid + 128] + red[tid + 192]);
    __syncthreads();
    red[tid] = lq; __syncthreads();
    if (tid < 64) atomicAdd(&stats[64 + tid], red[tid] + red[tid + 64] + red[tid + 128] + red[tid + 192]);
}

// ---------------------------------------------------------------------------
// BN finalize: alpha = g*rsqrt(var+eps), beta = be - mean*alpha
__global__ void k_bnfin(const float* __restrict__ stats, const float* __restrict__ g,
                        const float* __restrict__ be, float* __restrict__ coef, float invN) {
    int c = threadIdx.x;
    float m = stats[c] * invN;
    float var = stats[64 + c] * invN - m * m;
    float a = g[c] * rsqrtf(var + EPS);
    coef[c] = a;
    coef[64 + c] = be[c] - m * a;
}

// BN apply + ReLU, in place, float4-vectorized (64 channels => 16 float4/row)
__global__ void k_bnrelu(float* __restrict__ h, const float* __restrict__ coef, long long total4) {
    long long i = (long long)blockIdx.x * blockDim.x + threadIdx.x;
    if (i >= total4) return;
    float4 v = ((float4*)h)[i];
    int c = (int)((i * 4) & 63);
    v.x = fmaxf(0.f, fmaf(v.x, coef[c],     coef[64 + c]));
    v.y = fmaxf(0.f, fmaf(v.y, coef[c + 1], coef[65 + c]));
    v.z = fmaxf(0.f, fmaf(v.z, coef[c + 2], coef[66 + c]));
    v.w = fmaxf(0.f, fmaf(v.w, coef[c + 3], coef[67 + c]));
    ((float4*)h)[i] = v;
}

// BN apply + ReLU + residual: h = relu(h*a+b) + r, in place on h
__global__ void k_bnrelu_res(float* __restrict__ h, const float* __restrict__ r,
                             const float* __restrict__ coef, long long total4) {
    long long i = (long long)blockIdx.x * blockDim.x + threadIdx.x;
    if (i >= total4) return;
    float4 v = ((float4*)h)[i];
    float4 rv = ((const float4*)r)[i];
    int c = (int)((i * 4) & 63);
    v.x = fmaxf(0.f, fmaf(v.x, coef[c],     coef[64 + c])) + rv.x;
    v.y = fmaxf(0.f, fmaf(v.y, coef[c + 1], coef[65 + c])) + rv.y;
    v.z = fmaxf(0.f, fmaf(v.z, coef[c + 2], coef[66 + c])) + rv.z;
    v.w = fmaxf(0.f, fmaf(v.w, coef[c + 3], coef[67 + c])) + rv.w;
    ((float4*)h)[i] = v;
}

// ---------------------------------------------------------------------------
// Layer-2 scatter: agg2[dst, c] += x1[src, c]; one wave = one edge's 64 channels
__global__ void k_scatter2(const float* __restrict__ x1, const int* __restrict__ ei,
                           const int* __restrict__ flag, int E, float* __restrict__ agg2) {
    int t = blockIdx.x * blockDim.x + threadIdx.x;
    if (t >= E * 64) return;
    int e = t >> 6, c = t & 63;
    int f = *flag, s, d;
    load_edge(ei, E, e, f, s, d);
    atomicAdd(&agg2[(long long)d * 64 + c], x1[(long long)s * 64 + c]);
}

// ---------------------------------------------------------------------------
// Layer-2 dense: h2 = (agg2*inv)@W2l + b2 + x1@W2r, in place on agg2 buffer.
// NOTE: agg2/h2 alias (same buffer); row i is read fully into registers
// before being written, and each row is owned by exactly one wave.
__global__ __launch_bounds__(256) void k_dense2(
    const float* agg2, const float* __restrict__ x1,
    const float* __restrict__ invd,
    const float* __restrict__ W2l, const float* __restrict__ b2,
    const float* __restrict__ W2r,
    float* h2, float* __restrict__ stats, int n) {
    __shared__ float sWl[4096];
    __shared__ float sWr[4096];
    int tid = threadIdx.x;
    for (int i = tid; i < 4096; i += 256) { sWl[i] = W2l[i]; sWr[i] = W2r[i]; }
    __syncthreads();
    int c = tid & 63, w = tid >> 6;
    float bb = b2[c];
    float ls = 0.f, lq = 0.f;
    for (int i = blockIdx.x * 4 + w; i < n; i += gridDim.x * 4) {
        float inv = invd[i];
        float a = agg2[(long long)i * 64 + c] * inv;
        float xv = x1[(long long)i * 64 + c];
        float acc = bb;
#pragma unroll
        for (int k = 0; k < 64; ++k) {
            float av = __shfl(a, k, 64);
            float xk = __shfl(xv, k, 64);
            acc = fmaf(av, sWl[k * 64 + c], acc);
            acc = fmaf(xk, sWr[k * 64 + c], acc);
        }
        h2[(long long)i * 64 + c] = acc;
        ls += acc; lq += acc * acc;
    }
    __shared__ float red[256];
    red[tid] = ls; __syncthreads();
    if (tid < 64) atomicAdd(&stats[tid], red[tid] + red[tid + 64] + red[tid + 128] + red[tid + 192]);
    __syncthreads();
    red[tid] = lq; __syncthreads();
    if (tid < 64) atomicAdd(&stats[64 + tid], red[tid] + red[tid + 64] + red[tid + 128] + red[tid + 192]);
}

// ---------------------------------------------------------------------------
// Layer-3: per-node scalars t = x2 . W3l, v = x2 . W3r (wave per node)
__global__ __launch_bounds__(256) void k_dot3(
    const float* __restrict__ x2, const float* __restrict__ W3l,
    const float* __restrict__ W3r,
    float* __restrict__ t, float* __restrict__ v, int n) {
    int tid = threadIdx.x, c = tid & 63, w = tid >> 6;
    float wl = W3l[c], wr = W3r[c];
    for (int i = blockIdx.x * 4 + w; i < n; i += gridDim.x * 4) {
        float xv = x2[(long long)i * 64 + c];
        float tt = xv * wl, vv = xv * wr;
        for (int o = 32; o > 0; o >>= 1) {
            tt += __shfl_xor(tt, o, 64);
            vv += __shfl_xor(vv, o, 64);
        }
        if (c == 0) { t[i] = tt; v[i] = vv; }
    }
}

__global__ void k_scatter3(const float* __restrict__ t, const int* __restrict__ ei,
                           const int* __restrict__ flag, int E, float* __restrict__ agg3) {
    int e = blockIdx.x * blockDim.x + threadIdx.x;
    if (e >= E) return;
    int f = *flag, s, d;
    load_edge(ei, E, e, f, s, d);
    atomicAdd(&agg3[d], t[s]);
}

__global__ void k_final(const float* __restrict__ agg3, const float* __restrict__ invd,
                        const float* __restrict__ v, const float* __restrict__ b3,
                        float* __restrict__ out, int n) {
    int i = blockIdx.x * blockDim.x + threadIdx.x;
    if (i < n) out[i] = fmaf(agg3[i], invd[i], b3[0] + v[i]);
}

// ---------------------------------------------------------------------------
extern "C" void kernel_launch(void* const* d_in, const int* in_sizes, int n_in,
                              void* d_out, int out_size, void* d_ws, size_t ws_size,
                              hipStream_t stream) {
    const float* x   = (const float*)d_in[0];
    const int*   ei  = (const int*)d_in[1];
    const float* W1l = (const float*)d_in[2];
    const float* b1  = (const float*)d_in[3];
    const float* W1r = (const float*)d_in[4];
    const float* g1  = (const float*)d_in[5];
    const float* be1 = (const float*)d_in[6];
    const float* W2l = (const float*)d_in[7];
    const float* b2  = (const float*)d_in[8];
    const float* W2r = (const float*)d_in[9];
    const float* g2  = (const float*)d_in[10];
    const float* be2 = (const float*)d_in[11];
    const float* W3l = (const float*)d_in[12];
    const float* b3  = (const float*)d_in[13];
    const float* W3r = (const float*)d_in[14];

    int N = in_sizes[0] / 2;       // x is (N, 2)
    int E = in_sizes[1] / 2;       // edge_index is (2, E) (element count same for i32/i64)

    float* ws   = (float*)d_ws;
    size_t nn   = (size_t)N;
    float* deg  = ws;               // N      (becomes invdeg)
    float* agg1 = ws + nn;          // 2N
    float* B1   = ws + 3 * nn;      // 64N    h1 -> x1
    float* B2   = ws + 67 * nn;     // 64N    agg2 -> h2 -> x2
    float* tb   = ws + 131 * nn;    // N
    float* vb   = ws + 132 * nn;    // N
    float* agg3 = ws + 133 * nn;    // N
    float* stats = ws + 134 * nn;   // 256: s1,q1,s2,q2
    float* coef  = stats + 256;     // 256: a1,b1,a2,b2
    int*   flag  = (int*)(coef + 256);

    // zero the accumulators used this launch
    hipMemsetAsync(deg, 0, 3 * nn * sizeof(float), stream);         // deg + agg1
    hipMemsetAsync(B2, 0, 64 * nn * sizeof(float), stream);          // agg2
    hipMemsetAsync(agg3, 0, nn * sizeof(float), stream);
    hipMemsetAsync(stats, 0, 256 * sizeof(float), stream);

    k_detect<<<1, 1, 0, stream>>>(ei, flag);

    int ge = (E + 255) / 256;
    k_scatter1<<<ge, 256, 0, stream>>>(x, ei, flag, E, agg1, deg);
    k_invdeg<<<(N + 255) / 256, 256, 0, stream>>>(deg, N);
    k_dense1<<<1024, 256, 0, stream>>>(x, agg1, deg, W1l, b1, W1r, B1, stats, N);
    k_bnfin<<<1, 64, 0, stream>>>(stats, g1, be1, coef, 1.0f / (float)N);

    long long tot4 = (long long)N * 16;
    int g4 = (int)((tot4 + 255) / 256);
    k_bnrelu<<<g4, 256, 0, stream>>>(B1, coef, tot4);

    long long t2 = (long long)E * 64;
    k_scatter2<<<(int)((t2 + 255) / 256), 256, 0, stream>>>(B1, ei, flag, E, B2);
    k_dense2<<<2048, 256, 0, stream>>>(B2, B1, deg, W2l, b2, W2r, B2, stats + 128, N);
    k_bnfin<<<1, 64, 0, stream>>>(stats + 128, g2, be2, coef + 128, 1.0f / (float)N);
    k_bnrelu_res<<<g4, 256, 0, stream>>>(B2, B1, coef + 128, tot4);

    k_dot3<<<2048, 256, 0, stream>>>(B2, W3l, W3r, tb, vb, N);
    k_scatter3<<<ge, 256, 0, stream>>>(tb, ei, flag, E, agg3);
    k_final<<<(N + 255) / 256, 256, 0, stream>>>(agg3, deg, vb, b3, (float*)d_out, N);
}

// Round 2
// 1010.092 us; speedup vs baseline: 1.4632x; 1.4632x over previous
//
#include <hip/hip_runtime.h>

#define EPS 1e-5f

typedef __attribute__((ext_vector_type(8))) short bf16x8;
typedef __attribute__((ext_vector_type(4))) float f32x4;

// ---------------------------------------------------------------------------
// Edge-index dtype detection: JAX may emit int32 (x64 disabled) or int64.
__global__ void k_detect(const int* __restrict__ ei, int* __restrict__ flag) {
    if (blockIdx.x == 0 && threadIdx.x == 0) {
        int is64 = 1;
        for (int k = 0; k < 16; ++k) is64 &= (ei[2 * k + 1] == 0) ? 1 : 0;
        *flag = is64;
    }
}

__device__ __forceinline__ void load_edge(const int* __restrict__ ei, int E, int e,
                                          int f, int& s, int& d) {
    if (f) { s = ei[2 * e]; d = ei[2 * E + 2 * e]; }
    else   { s = ei[e];     d = ei[E + e]; }
}

// ---------------------------------------------------------------------------
__global__ void k_scatter1(const float* __restrict__ x, const int* __restrict__ ei,
                           const int* __restrict__ flag, int E,
                           float* __restrict__ agg1, float* __restrict__ deg) {
    int e = blockIdx.x * blockDim.x + threadIdx.x;
    if (e >= E) return;
    int f = *flag, s, d;
    load_edge(ei, E, e, f, s, d);
    atomicAdd(&agg1[2 * d],     x[2 * s]);
    atomicAdd(&agg1[2 * d + 1], x[2 * s + 1]);
    atomicAdd(&deg[d], 1.0f);
}

__global__ void k_invdeg(float* __restrict__ deg, int n) {
    int i = blockIdx.x * blockDim.x + threadIdx.x;
    if (i < n) deg[i] = 1.0f / fmaxf(deg[i], 1.0f);
}

// ---------------------------------------------------------------------------
// Layer-1 dense (K=2, trivial): h1 = (agg1*inv)@W1l + b1 + x@W1r, plus BN stats
__global__ __launch_bounds__(256) void k_dense1(
    const float* __restrict__ x, const float* __restrict__ agg1,
    const float* __restrict__ invd,
    const float* __restrict__ W1l, const float* __restrict__ b1,
    const float* __restrict__ W1r,
    float* __restrict__ h1, float* __restrict__ stats, int n) {
    int tid = threadIdx.x, c = tid & 63, w = tid >> 6;
    float wl0 = W1l[c], wl1 = W1l[64 + c];
    float wr0 = W1r[c], wr1 = W1r[64 + c];
    float bb = b1[c];
    float ls = 0.f, lq = 0.f;
    for (int i = blockIdx.x * 4 + w; i < n; i += gridDim.x * 4) {
        float inv = invd[i];
        float a0 = agg1[2 * i] * inv, a1 = agg1[2 * i + 1] * inv;
        float x0 = x[2 * i], x1v = x[2 * i + 1];
        float h = fmaf(a0, wl0, fmaf(a1, wl1, fmaf(x0, wr0, fmaf(x1v, wr1, bb))));
        h1[(long long)i * 64 + c] = h;
        ls += h; lq += h * h;
    }
    __shared__ float red[256];
    red[tid] = ls; __syncthreads();
    if (tid < 64) atomicAdd(&stats[tid], red[tid] + red[tid + 64] + red[tid + 128] + red[tid + 192]);
    __syncthreads();
    red[tid] = lq; __syncthreads();
    if (tid < 64) atomicAdd(&stats[64 + tid], red[tid] + red[tid + 64] + red[tid + 128] + red[tid + 192]);
}

// ---------------------------------------------------------------------------
__global__ void k_bnfin(const float* __restrict__ stats, const float* __restrict__ g,
                        const float* __restrict__ be, float* __restrict__ coef, float invN) {
    int c = threadIdx.x;
    float m = stats[c] * invN;
    float var = stats[64 + c] * invN - m * m;
    float a = g[c] * rsqrtf(var + EPS);
    coef[c] = a;
    coef[64 + c] = be[c] - m * a;
}

__global__ void k_bnrelu(float* __restrict__ h, const float* __restrict__ coef, long long total4) {
    long long i = (long long)blockIdx.x * blockDim.x + threadIdx.x;
    if (i >= total4) return;
    float4 v = ((float4*)h)[i];
    int c = (int)((i * 4) & 63);
    v.x = fmaxf(0.f, fmaf(v.x, coef[c],     coef[64 + c]));
    v.y = fmaxf(0.f, fmaf(v.y, coef[c + 1], coef[65 + c]));
    v.z = fmaxf(0.f, fmaf(v.z, coef[c + 2], coef[66 + c]));
    v.w = fmaxf(0.f, fmaf(v.w, coef[c + 3], coef[67 + c]));
    ((float4*)h)[i] = v;
}

__global__ void k_bnrelu_res(float* __restrict__ h, const float* __restrict__ r,
                             const float* __restrict__ coef, long long total4) {
    long long i = (long long)blockIdx.x * blockDim.x + threadIdx.x;
    if (i >= total4) return;
    float4 v = ((float4*)h)[i];
    float4 rv = ((const float4*)r)[i];
    int c = (int)((i * 4) & 63);
    v.x = fmaxf(0.f, fmaf(v.x, coef[c],     coef[64 + c])) + rv.x;
    v.y = fmaxf(0.f, fmaf(v.y, coef[c + 1], coef[65 + c])) + rv.y;
    v.z = fmaxf(0.f, fmaf(v.z, coef[c + 2], coef[66 + c])) + rv.z;
    v.w = fmaxf(0.f, fmaf(v.w, coef[c + 3], coef[67 + c])) + rv.w;
    ((float4*)h)[i] = v;
}

// ---------------------------------------------------------------------------
__global__ void k_scatter2(const float* __restrict__ x1, const int* __restrict__ ei,
                           const int* __restrict__ flag, int E, float* __restrict__ agg2) {
    int t = blockIdx.x * blockDim.x + threadIdx.x;
    if (t >= E * 64) return;
    int e = t >> 6, c = t & 63;
    int f = *flag, s, d;
    load_edge(ei, E, e, f, s, d);
    atomicAdd(&agg2[(long long)d * 64 + c], x1[(long long)s * 64 + c]);
}

// ---------------------------------------------------------------------------
// Layer-2 dense via MFMA (bf16 inputs, f32 accumulate).
// C[i][c] = sum_k A[i][k] W[k][c], A = [agg2*inv | x1] (K=128), W = [W2l; W2r].
// Per wave: 16-node tile, 4 K-steps x 4 N-steps of mfma_f32_16x16x32_bf16.
// W fragments live entirely in VGPRs (64 regs), loaded once per wave.
// A/B layout: 16-dim = lane&15, k = (lane>>4)*8 + j (j contiguous).
// C/D layout: col = lane&15, row = (lane>>4)*4 + reg.
// NOTE: agg2/h2 alias the same buffer (no __restrict__); each row is read
// fully before its wave writes it, and rows are wave-exclusive.
__device__ __forceinline__ short f2bf(float f) {
    unsigned u = __float_as_uint(f);
    u += 0x7fffu + ((u >> 16) & 1u);
    return (short)(u >> 16);
}

__device__ __forceinline__ bf16x8 load8_bf(const float* p, float scale) {
    float4 f0 = ((const float4*)p)[0];
    float4 f1 = ((const float4*)p)[1];
    bf16x8 r;
    r[0] = f2bf(f0.x * scale); r[1] = f2bf(f0.y * scale);
    r[2] = f2bf(f0.z * scale); r[3] = f2bf(f0.w * scale);
    r[4] = f2bf(f1.x * scale); r[5] = f2bf(f1.y * scale);
    r[6] = f2bf(f1.z * scale); r[7] = f2bf(f1.w * scale);
    return r;
}

__global__ __launch_bounds__(256) void k_dense2_mfma(
    const float* agg2, const float* __restrict__ x1,
    const float* __restrict__ invd,
    const float* __restrict__ W2l, const float* __restrict__ b2,
    const float* __restrict__ W2r,
    float* h2, float* __restrict__ stats, int n) {
    int tid = threadIdx.x;
    int w = tid >> 6;
    int l = tid & 63;
    int ln = l & 15, kg = l >> 4;

    // B-operand fragments for W (once per wave)
    bf16x8 wf[4][4];
#pragma unroll
    for (int ks = 0; ks < 4; ++ks) {
#pragma unroll
        for (int cs = 0; cs < 4; ++cs) {
            int kbase = ks * 32 + kg * 8;
            int c = cs * 16 + ln;
            bf16x8 t;
#pragma unroll
            for (int j = 0; j < 8; ++j) {
                int k = kbase + j;
                float wv = (k < 64) ? W2l[k * 64 + c] : W2r[(k - 64) * 64 + c];
                t[j] = f2bf(wv);
            }
            wf[ks][cs] = t;
        }
    }
    float bb[4];
#pragma unroll
    for (int cs = 0; cs < 4; ++cs) bb[cs] = b2[cs * 16 + ln];

    float ls[4] = {0.f, 0.f, 0.f, 0.f};
    float lq[4] = {0.f, 0.f, 0.f, 0.f};

    int nt = (n + 15) >> 4;
    for (int tile = blockIdx.x * 4 + w; tile < nt; tile += gridDim.x * 4) {
        int i0 = tile << 4;
        int row = i0 + ln;
        bool v = row < n;
        int rr = v ? row : (n - 1);
        float inv = v ? invd[rr] : 0.f;
        float xs = v ? 1.f : 0.f;
        const float* ar = agg2 + (size_t)rr * 64 + kg * 8;
        const float* xr = x1   + (size_t)rr * 64 + kg * 8;
        bf16x8 a0 = load8_bf(ar,      inv);
        bf16x8 a1 = load8_bf(ar + 32, inv);
        bf16x8 a2 = load8_bf(xr,      xs);
        bf16x8 a3 = load8_bf(xr + 32, xs);

        f32x4 acc[4];
#pragma unroll
        for (int cs = 0; cs < 4; ++cs) acc[cs] = (f32x4){0.f, 0.f, 0.f, 0.f};
#pragma unroll
        for (int cs = 0; cs < 4; ++cs) {
            acc[cs] = __builtin_amdgcn_mfma_f32_16x16x32_bf16(a0, wf[0][cs], acc[cs], 0, 0, 0);
            acc[cs] = __builtin_amdgcn_mfma_f32_16x16x32_bf16(a1, wf[1][cs], acc[cs], 0, 0, 0);
            acc[cs] = __builtin_amdgcn_mfma_f32_16x16x32_bf16(a2, wf[2][cs], acc[cs], 0, 0, 0);
            acc[cs] = __builtin_amdgcn_mfma_f32_16x16x32_bf16(a3, wf[3][cs], acc[cs], 0, 0, 0);
        }
#pragma unroll
        for (int cs = 0; cs < 4; ++cs) {
#pragma unroll
            for (int r = 0; r < 4; ++r) {
                int orow = i0 + kg * 4 + r;
                if (orow < n) {
                    float h = acc[cs][r] + bb[cs];
                    h2[(size_t)orow * 64 + cs * 16 + ln] = h;
                    ls[cs] += h; lq[cs] += h * h;
                }
            }
        }
    }
    // BN stats: channels = cs*16+ln; lanes {l, l^16, l^32, l^48} share a channel
#pragma unroll
    for (int cs = 0; cs < 4; ++cs) {
        float s = ls[cs], q = lq[cs];
        s += __shfl_xor(s, 16, 64); s += __shfl_xor(s, 32, 64);
        q += __shfl_xor(q, 16, 64); q += __shfl_xor(q, 32, 64);
        if (kg == 0) {
            atomicAdd(&stats[cs * 16 + ln], s);
            atomicAdd(&stats[64 + cs * 16 + ln], q);
        }
    }
}

// ---------------------------------------------------------------------------
__global__ __launch_bounds__(256) void k_dot3(
    const float* __restrict__ x2, const float* __restrict__ W3l,
    const float* __restrict__ W3r,
    float* __restrict__ t, float* __restrict__ v, int n) {
    int tid = threadIdx.x, c = tid & 63, w = tid >> 6;
    float wl = W3l[c], wr = W3r[c];
    for (int i = blockIdx.x * 4 + w; i < n; i += gridDim.x * 4) {
        float xv = x2[(long long)i * 64 + c];
        float tt = xv * wl, vv = xv * wr;
        for (int o = 32; o > 0; o >>= 1) {
            tt += __shfl_xor(tt, o, 64);
            vv += __shfl_xor(vv, o, 64);
        }
        if (c == 0) { t[i] = tt; v[i] = vv; }
    }
}

__global__ void k_scatter3(const float* __restrict__ t, const int* __restrict__ ei,
                           const int* __restrict__ flag, int E, float* __restrict__ agg3) {
    int e = blockIdx.x * blockDim.x + threadIdx.x;
    if (e >= E) return;
    int f = *flag, s, d;
    load_edge(ei, E, e, f, s, d);
    atomicAdd(&agg3[d], t[s]);
}

__global__ void k_final(const float* __restrict__ agg3, const float* __restrict__ invd,
                        const float* __restrict__ v, const float* __restrict__ b3,
                        float* __restrict__ out, int n) {
    int i = blockIdx.x * blockDim.x + threadIdx.x;
    if (i < n) out[i] = fmaf(agg3[i], invd[i], b3[0] + v[i]);
}

// ---------------------------------------------------------------------------
extern "C" void kernel_launch(void* const* d_in, const int* in_sizes, int n_in,
                              void* d_out, int out_size, void* d_ws, size_t ws_size,
                              hipStream_t stream) {
    const float* x   = (const float*)d_in[0];
    const int*   ei  = (const int*)d_in[1];
    const float* W1l = (const float*)d_in[2];
    const float* b1  = (const float*)d_in[3];
    const float* W1r = (const float*)d_in[4];
    const float* g1  = (const float*)d_in[5];
    const float* be1 = (const float*)d_in[6];
    const float* W2l = (const float*)d_in[7];
    const float* b2  = (const float*)d_in[8];
    const float* W2r = (const float*)d_in[9];
    const float* g2  = (const float*)d_in[10];
    const float* be2 = (const float*)d_in[11];
    const float* W3l = (const float*)d_in[12];
    const float* b3  = (const float*)d_in[13];
    const float* W3r = (const float*)d_in[14];

    int N = in_sizes[0] / 2;
    int E = in_sizes[1] / 2;

    float* ws   = (float*)d_ws;
    size_t nn   = (size_t)N;
    float* deg  = ws;               // N      (becomes invdeg)
    float* agg1 = ws + nn;          // 2N
    float* B1   = ws + 3 * nn;      // 64N    h1 -> x1
    float* B2   = ws + 67 * nn;     // 64N    agg2 -> h2 -> x2
    float* tb   = ws + 131 * nn;    // N
    float* vb   = ws + 132 * nn;    // N
    float* agg3 = ws + 133 * nn;    // N
    float* stats = ws + 134 * nn;   // 256: s1,q1,s2,q2
    float* coef  = stats + 256;     // 256: a1,b1,a2,b2
    int*   flag  = (int*)(coef + 256);

    hipMemsetAsync(deg, 0, 3 * nn * sizeof(float), stream);   // deg + agg1
    hipMemsetAsync(B2, 0, 64 * nn * sizeof(float), stream);   // agg2
    hipMemsetAsync(agg3, 0, nn * sizeof(float), stream);
    hipMemsetAsync(stats, 0, 256 * sizeof(float), stream);

    k_detect<<<1, 1, 0, stream>>>(ei, flag);

    int ge = (E + 255) / 256;
    k_scatter1<<<ge, 256, 0, stream>>>(x, ei, flag, E, agg1, deg);
    k_invdeg<<<(N + 255) / 256, 256, 0, stream>>>(deg, N);
    k_dense1<<<1024, 256, 0, stream>>>(x, agg1, deg, W1l, b1, W1r, B1, stats, N);
    k_bnfin<<<1, 64, 0, stream>>>(stats, g1, be1, coef, 1.0f / (float)N);

    long long tot4 = (long long)N * 16;
    int g4 = (int)((tot4 + 255) / 256);
    k_bnrelu<<<g4, 256, 0, stream>>>(B1, coef, tot4);

    long long t2 = (long long)E * 64;
    k_scatter2<<<(int)((t2 + 255) / 256), 256, 0, stream>>>(B1, ei, flag, E, B2);
    k_dense2_mfma<<<2048, 256, 0, stream>>>(B2, B1, deg, W2l, b2, W2r, B2, stats + 128, N);
    k_bnfin<<<1, 64, 0, stream>>>(stats + 128, g2, be2, coef + 128, 1.0f / (float)N);
    k_bnrelu_res<<<g4, 256, 0, stream>>>(B2, B1, coef + 128, tot4);

    k_dot3<<<2048, 256, 0, stream>>>(B2, W3l, W3r, tb, vb, N);
    k_scatter3<<<ge, 256, 0, stream>>>(tb, ei, flag, E, agg3);
    k_final<<<(N + 255) / 256, 256, 0, stream>>>(agg3, deg, vb, b3, (float*)d_out, N);
}

// Round 4
// 895.313 us; speedup vs baseline: 1.6508x; 1.1282x over previous
//
#include <hip/hip_runtime.h>

#define EPS 1e-5f

typedef __attribute__((ext_vector_type(8))) short bf16x8;
typedef __attribute__((ext_vector_type(4))) float f32x4;

// ---------------------------------------------------------------------------
// Edge-index dtype detection: JAX may emit int32 (x64 disabled) or int64.
__global__ void k_detect(const int* __restrict__ ei, int* __restrict__ flag) {
    if (blockIdx.x == 0 && threadIdx.x == 0) {
        int is64 = 1;
        for (int k = 0; k < 16; ++k) is64 &= (ei[2 * k + 1] == 0) ? 1 : 0;
        *flag = is64;
    }
}

__device__ __forceinline__ void load_edge(const int* __restrict__ ei, int E, int e,
                                          int f, int& s, int& d) {
    if (f) { s = ei[2 * e]; d = ei[2 * E + 2 * e]; }
    else   { s = ei[e];     d = ei[E + e]; }
}

// ---------------------------------------------------------------------------
// CSR build: histogram -> exclusive scan (3 kernels) -> fill
__global__ void k_hist(const int* __restrict__ ei, const int* __restrict__ flag,
                       int E, int* __restrict__ cnt) {
    int e = blockIdx.x * blockDim.x + threadIdx.x;
    if (e >= E) return;
    int f = *flag;
    int d = f ? ei[2 * E + 2 * e] : ei[E + e];
    atomicAdd(&cnt[d], 1);
}

// inclusive scan of one value per thread across a 256-thread block
__device__ __forceinline__ int block_incl_scan(int v, int tid, int* total) {
    __shared__ int wsum[4];
    __shared__ int tot;
#pragma unroll
    for (int o = 1; o < 64; o <<= 1) {
        int u = __shfl_up(v, o, 64);
        if ((tid & 63) >= o) v += u;
    }
    if ((tid & 63) == 63) wsum[tid >> 6] = v;
    __syncthreads();
    int w = tid >> 6, add = 0;
    if (w > 0) add += wsum[0];
    if (w > 1) add += wsum[1];
    if (w > 2) add += wsum[2];
    v += add;
    if (tid == 255) tot = v;
    __syncthreads();
    *total = tot;
    __syncthreads();
    return v;
}

// Pass A: per-block (1024 elements) sums
__global__ __launch_bounds__(256) void k_scanA(const int* __restrict__ cnt, int n,
                                               int* __restrict__ bsums) {
    int tid = threadIdx.x;
    int idx = blockIdx.x * 1024 + tid * 4;
    int s = 0;
#pragma unroll
    for (int k = 0; k < 4; ++k) { int i = idx + k; if (i < n) s += cnt[i]; }
#pragma unroll
    for (int o = 32; o > 0; o >>= 1) s += __shfl_xor(s, o, 64);
    __shared__ int ws[4];
    if ((tid & 63) == 0) ws[tid >> 6] = s;
    __syncthreads();
    if (tid == 0) bsums[blockIdx.x] = ws[0] + ws[1] + ws[2] + ws[3];
}

// Pass B: exclusive scan of block sums (single block), writes rowptr[N]=E
__global__ __launch_bounds__(256) void k_scanB(int* __restrict__ bsums, int nb,
                                               int* __restrict__ rowptr, int N) {
    int tid = threadIdx.x;
    __shared__ int sh_carry;
    if (tid == 0) sh_carry = 0;
    __syncthreads();
    int niter = (nb + 255) / 256;
    for (int it = 0; it < niter; ++it) {
        int i = it * 256 + tid;
        int v = (i < nb) ? bsums[i] : 0;
        int tot;
        int inc = block_incl_scan(v, tid, &tot);
        int carry = sh_carry;
        if (i < nb) bsums[i] = carry + inc - v;   // exclusive offset for block i
        __syncthreads();
        if (tid == 0) sh_carry = carry + tot;
        __syncthreads();
    }
    if (tid == 0) rowptr[N] = sh_carry;
}

// Pass C: in-place exclusive scan of cnt -> rowptr (same buffer), also cursor
__global__ __launch_bounds__(256) void k_scanC(int* __restrict__ cnt_rowptr, int n,
                                               const int* __restrict__ bsums,
                                               int* __restrict__ cursor) {
    int tid = threadIdx.x;
    int idx = blockIdx.x * 1024 + tid * 4;
    int v[4]; int s = 0;
#pragma unroll
    for (int k = 0; k < 4; ++k) { int i = idx + k; v[k] = (i < n) ? cnt_rowptr[i] : 0; s += v[k]; }
    int tot;
    int inc = block_incl_scan(s, tid, &tot);
    int off = bsums[blockIdx.x] + inc - s;
#pragma unroll
    for (int k = 0; k < 4; ++k) {
        int i = idx + k;
        if (i < n) { cnt_rowptr[i] = off; cursor[i] = off; off += v[k]; }
    }
}

__global__ void k_fill(const int* __restrict__ ei, const int* __restrict__ flag, int E,
                       int* __restrict__ cursor, int* __restrict__ csr) {
    int e = blockIdx.x * blockDim.x + threadIdx.x;
    if (e >= E) return;
    int f = *flag, s, d;
    load_edge(ei, E, e, f, s, d);
    int pos = atomicAdd(&cursor[d], 1);
    csr[pos] = s;
}

// ---------------------------------------------------------------------------
// Layer-1 gather: agg1[i,:] = mean over neighbors of x[src,:] (2 channels)
__global__ void k_gather1(const float* __restrict__ x, const int* __restrict__ rowptr,
                          const int* __restrict__ csr, float* __restrict__ agg1, int n) {
    int i = blockIdx.x * blockDim.x + threadIdx.x;
    if (i >= n) return;
    int r0 = rowptr[i], r1 = rowptr[i + 1];
    float s0 = 0.f, s1 = 0.f;
    for (int j = r0; j < r1; ++j) {
        int s = csr[j];
        s0 += x[2 * s]; s1 += x[2 * s + 1];
    }
    float inv = 1.f / fmaxf((float)(r1 - r0), 1.f);
    agg1[2 * i] = s0 * inv;
    agg1[2 * i + 1] = s1 * inv;
}

// ---------------------------------------------------------------------------
// Layer-1 dense (K=2): h1 = agg1@W1l + b1 + x@W1r (raw, pre-BN), plus BN stats
__global__ __launch_bounds__(256) void k_dense1(
    const float* __restrict__ x, const float* __restrict__ agg1,
    const float* __restrict__ W1l, const float* __restrict__ b1,
    const float* __restrict__ W1r,
    float* __restrict__ h1, float* __restrict__ stats, int n) {
    int tid = threadIdx.x, c = tid & 63, w = tid >> 6;
    float wl0 = W1l[c], wl1 = W1l[64 + c];
    float wr0 = W1r[c], wr1 = W1r[64 + c];
    float bb = b1[c];
    float ls = 0.f, lq = 0.f;
    for (int i = blockIdx.x * 4 + w; i < n; i += gridDim.x * 4) {
        float a0 = agg1[2 * i], a1 = agg1[2 * i + 1];
        float x0 = x[2 * i], x1v = x[2 * i + 1];
        float h = fmaf(a0, wl0, fmaf(a1, wl1, fmaf(x0, wr0, fmaf(x1v, wr1, bb))));
        h1[(long long)i * 64 + c] = h;
        ls += h; lq += h * h;
    }
    __shared__ float red[256];
    red[tid] = ls; __syncthreads();
    if (tid < 64) atomicAdd(&stats[tid], red[tid] + red[tid + 64] + red[tid + 128] + red[tid + 192]);
    __syncthreads();
    red[tid] = lq; __syncthreads();
    if (tid < 64) atomicAdd(&stats[64 + tid], red[tid] + red[tid + 64] + red[tid + 128] + red[tid + 192]);
}

// ---------------------------------------------------------------------------
__global__ void k_bnfin(const float* __restrict__ stats, const float* __restrict__ g,
                        const float* __restrict__ be, float* __restrict__ coef, float invN) {
    int c = threadIdx.x;
    float m = stats[c] * invN;
    float var = stats[64 + c] * invN - m * m;
    float a = g[c] * rsqrtf(var + EPS);
    coef[c] = a;
    coef[64 + c] = be[c] - m * a;
}

// ---------------------------------------------------------------------------
// Layer-2 gather: agg2[i,c] = mean over neighbors of relu(bn1(h1[src,c])).
// One wave per node; lane = channel. Coalesced 256B row reads, no atomics.
__global__ __launch_bounds__(256) void k_gather2(
    const float* __restrict__ h1, const int* __restrict__ rowptr,
    const int* __restrict__ csr, const float* __restrict__ coef1,
    float* __restrict__ agg2, int n) {
    int tid = threadIdx.x, c = tid & 63, w = tid >> 6;
    int i = blockIdx.x * 4 + w;
    if (i >= n) return;
    float a1 = coef1[c], b1 = coef1[64 + c];
    int r0 = rowptr[i], r1 = rowptr[i + 1];
    float s = 0.f;
    int j = r0;
    for (; j + 1 < r1; j += 2) {
        int s0 = csr[j], s1 = csr[j + 1];
        float v0 = h1[(size_t)s0 * 64 + c];
        float v1 = h1[(size_t)s1 * 64 + c];
        s += fmaxf(0.f, fmaf(v0, a1, b1)) + fmaxf(0.f, fmaf(v1, a1, b1));
    }
    if (j < r1) {
        int s0 = csr[j];
        float v0 = h1[(size_t)s0 * 64 + c];
        s += fmaxf(0.f, fmaf(v0, a1, b1));
    }
    float inv = 1.f / fmaxf((float)(r1 - r0), 1.f);
    agg2[(size_t)i * 64 + c] = s * inv;
}

// ---------------------------------------------------------------------------
// Layer-2 dense via MFMA. C[i][c] = sum_k A[i][k] W[k][c],
// A = [agg2 | relu(bn1(h1))] (K=128), W = [W2l; W2r]. Writes raw h2 + stats.
__device__ __forceinline__ short f2bf(float f) {
    unsigned u = __float_as_uint(f);
    u += 0x7fffu + ((u >> 16) & 1u);
    return (short)(u >> 16);
}

__device__ __forceinline__ bf16x8 load8_bf(const float* p) {
    float4 f0 = ((const float4*)p)[0];
    float4 f1 = ((const float4*)p)[1];
    bf16x8 r;
    r[0] = f2bf(f0.x); r[1] = f2bf(f0.y); r[2] = f2bf(f0.z); r[3] = f2bf(f0.w);
    r[4] = f2bf(f1.x); r[5] = f2bf(f1.y); r[6] = f2bf(f1.z); r[7] = f2bf(f1.w);
    return r;
}

__device__ __forceinline__ bf16x8 load8_bn(const float* p, const float* ca, const float* cb) {
    float4 f0 = ((const float4*)p)[0];
    float4 f1 = ((const float4*)p)[1];
    bf16x8 r;
    r[0] = f2bf(fmaxf(0.f, fmaf(f0.x, ca[0], cb[0])));
    r[1] = f2bf(fmaxf(0.f, fmaf(f0.y, ca[1], cb[1])));
    r[2] = f2bf(fmaxf(0.f, fmaf(f0.z, ca[2], cb[2])));
    r[3] = f2bf(fmaxf(0.f, fmaf(f0.w, ca[3], cb[3])));
    r[4] = f2bf(fmaxf(0.f, fmaf(f1.x, ca[4], cb[4])));
    r[5] = f2bf(fmaxf(0.f, fmaf(f1.y, ca[5], cb[5])));
    r[6] = f2bf(fmaxf(0.f, fmaf(f1.z, ca[6], cb[6])));
    r[7] = f2bf(fmaxf(0.f, fmaf(f1.w, ca[7], cb[7])));
    return r;
}

__global__ __launch_bounds__(256) void k_dense2_mfma(
    const float* agg2, const float* __restrict__ h1,
    const float* __restrict__ coef1,
    const float* __restrict__ W2l, const float* __restrict__ b2,
    const float* __restrict__ W2r,
    float* h2, float* __restrict__ stats, int n) {
    int tid = threadIdx.x;
    int w = tid >> 6;
    int l = tid & 63;
    int ln = l & 15, kg = l >> 4;

    // B-operand fragments for W (once per wave)
    bf16x8 wf[4][4];
#pragma unroll
    for (int ks = 0; ks < 4; ++ks) {
#pragma unroll
        for (int cs = 0; cs < 4; ++cs) {
            int kbase = ks * 32 + kg * 8;
            int c = cs * 16 + ln;
            bf16x8 t;
#pragma unroll
            for (int j = 0; j < 8; ++j) {
                int k = kbase + j;
                float wv = (k < 64) ? W2l[k * 64 + c] : W2r[(k - 64) * 64 + c];
                t[j] = f2bf(wv);
            }
            wf[ks][cs] = t;
        }
    }
    float bb[4];
#pragma unroll
    for (int cs = 0; cs < 4; ++cs) bb[cs] = b2[cs * 16 + ln];

    // BN1 coefs for this lane's k-slice (k = kg*8+j and 32+kg*8+j)
    float c1a[16], c1b[16];
#pragma unroll
    for (int j = 0; j < 8; ++j) {
        c1a[j]     = coef1[kg * 8 + j];       c1b[j]     = coef1[64 + kg * 8 + j];
        c1a[8 + j] = coef1[32 + kg * 8 + j];  c1b[8 + j] = coef1[96 + kg * 8 + j];
    }

    float ls[4] = {0.f, 0.f, 0.f, 0.f};
    float lq[4] = {0.f, 0.f, 0.f, 0.f};

    int nt = (n + 15) >> 4;
    for (int tile = blockIdx.x * 4 + w; tile < nt; tile += gridDim.x * 4) {
        int i0 = tile << 4;
        int row = i0 + ln;
        int rr = (row < n) ? row : (n - 1);   // clamp; garbage rows never stored
        const float* ar = agg2 + (size_t)rr * 64 + kg * 8;
        const float* xr = h1   + (size_t)rr * 64 + kg * 8;
        bf16x8 a0 = load8_bf(ar);
        bf16x8 a1 = load8_bf(ar + 32);
        bf16x8 a2 = load8_bn(xr,      c1a,     c1b);
        bf16x8 a3 = load8_bn(xr + 32, c1a + 8, c1b + 8);

        f32x4 acc[4];
#pragma unroll
        for (int cs = 0; cs < 4; ++cs) acc[cs] = (f32x4){0.f, 0.f, 0.f, 0.f};
#pragma unroll
        for (int cs = 0; cs < 4; ++cs) {
            acc[cs] = __builtin_amdgcn_mfma_f32_16x16x32_bf16(a0, wf[0][cs], acc[cs], 0, 0, 0);
            acc[cs] = __builtin_amdgcn_mfma_f32_16x16x32_bf16(a1, wf[1][cs], acc[cs], 0, 0, 0);
            acc[cs] = __builtin_amdgcn_mfma_f32_16x16x32_bf16(a2, wf[2][cs], acc[cs], 0, 0, 0);
            acc[cs] = __builtin_amdgcn_mfma_f32_16x16x32_bf16(a3, wf[3][cs], acc[cs], 0, 0, 0);
        }
#pragma unroll
        for (int cs = 0; cs < 4; ++cs) {
#pragma unroll
            for (int r = 0; r < 4; ++r) {
                int orow = i0 + kg * 4 + r;
                if (orow < n) {
                    float h = acc[cs][r] + bb[cs];
                    h2[(size_t)orow * 64 + cs * 16 + ln] = h;
                    ls[cs] += h; lq[cs] += h * h;
                }
            }
        }
    }
#pragma unroll
    for (int cs = 0; cs < 4; ++cs) {
        float s = ls[cs], q = lq[cs];
        s += __shfl_xor(s, 16, 64); s += __shfl_xor(s, 32, 64);
        q += __shfl_xor(q, 16, 64); q += __shfl_xor(q, 32, 64);
        if (kg == 0) {
            atomicAdd(&stats[cs * 16 + ln], s);
            atomicAdd(&stats[64 + cs * 16 + ln], q);
        }
    }
}

// ---------------------------------------------------------------------------
// Finalize layer 2 + layer-3 projections, never materializing x2:
// x2 = relu(bn2(h2)) + relu(bn1(h1)); t = x2.W3l; v = x2.W3r
__global__ __launch_bounds__(256) void k_finalize(
    const float* __restrict__ h2, const float* __restrict__ h1,
    const float* __restrict__ coef1, const float* __restrict__ coef2,
    const float* __restrict__ W3l, const float* __restrict__ W3r,
    float* __restrict__ tb, float* __restrict__ vb, int n) {
    int tid = threadIdx.x, c = tid & 63, w = tid >> 6;
    int i = blockIdx.x * 4 + w;
    if (i >= n) return;
    float a1 = coef1[c], b1 = coef1[64 + c];
    float a2 = coef2[c], b2 = coef2[64 + c];
    float wl = W3l[c], wr = W3r[c];
    float h1v = h1[(size_t)i * 64 + c];
    float h2v = h2[(size_t)i * 64 + c];
    float x1v = fmaxf(0.f, fmaf(h1v, a1, b1));
    float x2v = fmaxf(0.f, fmaf(h2v, a2, b2)) + x1v;
    float t = x2v * wl, v = x2v * wr;
#pragma unroll
    for (int o = 32; o > 0; o >>= 1) {
        t += __shfl_xor(t, o, 64);
        v += __shfl_xor(v, o, 64);
    }
    if (c == 0) { tb[i] = t; vb[i] = v; }
}

// ---------------------------------------------------------------------------
// Layer-3 gather + output: out[i] = mean over neighbors of t[src] + v[i] + b3
__global__ void k_gather3(const float* __restrict__ tb, const float* __restrict__ vb,
                          const int* __restrict__ rowptr, const int* __restrict__ csr,
                          const float* __restrict__ b3, float* __restrict__ out, int n) {
    int i = blockIdx.x * blockDim.x + threadIdx.x;
    if (i >= n) return;
    int r0 = rowptr[i], r1 = rowptr[i + 1];
    float s = 0.f;
    for (int j = r0; j < r1; ++j) s += tb[csr[j]];
    float inv = 1.f / fmaxf((float)(r1 - r0), 1.f);
    out[i] = fmaf(s, inv, b3[0] + vb[i]);
}

// ---------------------------------------------------------------------------
// Workspace budget: ws_size = 256 MiB = 67,108,864 4-byte units (round-3 OOB
// post-mortem). Layout (units of 4 bytes, N=500k, E=1.25M):
//   B1     64N  = 32,000,000   h1 (raw, f32)
//   B2     64N  = 32,000,000   agg2 -> h2 (raw, f32)
//   R       2N  =  1,000,000   TIME-SHARED: cursor[N+1] -> agg1[2N] -> tb[N]+vb[N]
//   rowptr N+1  =    500,001
//   csr      E  =  1,250,000
//   bsums        =      2,048
//   stats+coef   =        512
//   flag         =         64
// total 66,752,625 units = 267,010,500 B  (1.4 MB slack)
extern "C" void kernel_launch(void* const* d_in, const int* in_sizes, int n_in,
                              void* d_out, int out_size, void* d_ws, size_t ws_size,
                              hipStream_t stream) {
    const float* x   = (const float*)d_in[0];
    const int*   ei  = (const int*)d_in[1];
    const float* W1l = (const float*)d_in[2];
    const float* b1  = (const float*)d_in[3];
    const float* W1r = (const float*)d_in[4];
    const float* g1  = (const float*)d_in[5];
    const float* be1 = (const float*)d_in[6];
    const float* W2l = (const float*)d_in[7];
    const float* b2  = (const float*)d_in[8];
    const float* W2r = (const float*)d_in[9];
    const float* g2  = (const float*)d_in[10];
    const float* be2 = (const float*)d_in[11];
    const float* W3l = (const float*)d_in[12];
    const float* b3  = (const float*)d_in[13];
    const float* W3r = (const float*)d_in[14];

    int N = in_sizes[0] / 2;
    int E = in_sizes[1] / 2;

    float* ws   = (float*)d_ws;
    size_t nn   = (size_t)N;
    float* B1    = ws;                     // 64N  h1 (raw)
    float* B2    = ws + 64 * nn;           // 64N  agg2 -> h2 (raw)
    float* R     = ws + 128 * nn;          // 2N   time-shared region
    int*   cursor = (int*)R;               //   phase 1: CSR build (N+1 ints)
    float* agg1   = R;                     //   phase 2: layer-1 agg (2N f32)
    float* tb     = R;                     //   phase 3: layer-3 t (N f32)
    float* vb     = R + nn;                //   phase 3: layer-3 v (N f32)
    int*   rowptr = (int*)(ws + 130 * nn); // N+1 (doubles as histogram cnt)
    int*   csr    = rowptr + (N + 1);      // E
    int*   bsums  = csr + E;               // 2048
    float* stats  = (float*)(bsums + 2048);// 256: s1,q1 | s2,q2
    float* coef   = stats + 256;           // 256: a1,b1 | a2,b2
    int*   flag   = (int*)(coef + 256);    // 64 (padded)

    hipMemsetAsync(rowptr, 0, (size_t)(N + 1) * sizeof(int), stream);
    hipMemsetAsync(stats, 0, 256 * sizeof(float), stream);

    k_detect<<<1, 1, 0, stream>>>(ei, flag);

    int ge = (E + 255) / 256;
    int nb = (N + 1023) / 1024;
    k_hist<<<ge, 256, 0, stream>>>(ei, flag, E, rowptr);
    k_scanA<<<nb, 256, 0, stream>>>(rowptr, N, bsums);
    k_scanB<<<1, 256, 0, stream>>>(bsums, nb, rowptr, N);
    k_scanC<<<nb, 256, 0, stream>>>(rowptr, N, bsums, cursor);
    k_fill<<<ge, 256, 0, stream>>>(ei, flag, E, cursor, csr);
    // cursor dead from here; R becomes agg1

    k_gather1<<<(N + 255) / 256, 256, 0, stream>>>(x, rowptr, csr, agg1, N);
    k_dense1<<<1024, 256, 0, stream>>>(x, agg1, W1l, b1, W1r, B1, stats, N);
    k_bnfin<<<1, 64, 0, stream>>>(stats, g1, be1, coef, 1.0f / (float)N);
    // agg1 dead after dense1

    int gw = (N + 3) / 4;  // wave-per-node kernels
    k_gather2<<<gw, 256, 0, stream>>>(B1, rowptr, csr, coef, B2, N);
    k_dense2_mfma<<<2048, 256, 0, stream>>>(B2, B1, coef, W2l, b2, W2r, B2, stats + 128, N);
    k_bnfin<<<1, 64, 0, stream>>>(stats + 128, g2, be2, coef + 128, 1.0f / (float)N);

    // R becomes tb/vb
    k_finalize<<<gw, 256, 0, stream>>>(B2, B1, coef, coef + 128, W3l, W3r, tb, vb, N);
    k_gather3<<<(N + 255) / 256, 256, 0, stream>>>(tb, vb, rowptr, csr, b3, (float*)d_out, N);
}

// Round 5
// 688.676 us; speedup vs baseline: 2.1461x; 1.3000x over previous
//
#include <hip/hip_runtime.h>

#define EPS 1e-5f

typedef __attribute__((ext_vector_type(8))) short bf16x8;
typedef __attribute__((ext_vector_type(4))) float f32x4;

__device__ __forceinline__ unsigned short f2bf(float f) {
    unsigned u = __float_as_uint(f);
    u += 0x7fffu + ((u >> 16) & 1u);
    return (unsigned short)(u >> 16);
}
__device__ __forceinline__ float bf2f(unsigned short s) {
    return __uint_as_float(((unsigned)s) << 16);
}

// ---------------------------------------------------------------------------
// Edge-index dtype detection: JAX may emit int32 (x64 disabled) or int64.
__global__ void k_detect(const int* __restrict__ ei, int* __restrict__ flag) {
    if (blockIdx.x == 0 && threadIdx.x == 0) {
        int is64 = 1;
        for (int k = 0; k < 16; ++k) is64 &= (ei[2 * k + 1] == 0) ? 1 : 0;
        *flag = is64;
    }
}

__device__ __forceinline__ void load_edge(const int* __restrict__ ei, int E, int e,
                                          int f, int& s, int& d) {
    if (f) { s = ei[2 * e]; d = ei[2 * E + 2 * e]; }
    else   { s = ei[e];     d = ei[E + e]; }
}

// ---------------------------------------------------------------------------
// CSR build: histogram -> exclusive scan (3 kernels) -> fill
__global__ void k_hist(const int* __restrict__ ei, const int* __restrict__ flag,
                       int E, int* __restrict__ cnt) {
    int e = blockIdx.x * blockDim.x + threadIdx.x;
    if (e >= E) return;
    int f = *flag;
    int d = f ? ei[2 * E + 2 * e] : ei[E + e];
    atomicAdd(&cnt[d], 1);
}

__device__ __forceinline__ int block_incl_scan(int v, int tid, int* total) {
    __shared__ int wsum[4];
    __shared__ int tot;
#pragma unroll
    for (int o = 1; o < 64; o <<= 1) {
        int u = __shfl_up(v, o, 64);
        if ((tid & 63) >= o) v += u;
    }
    if ((tid & 63) == 63) wsum[tid >> 6] = v;
    __syncthreads();
    int w = tid >> 6, add = 0;
    if (w > 0) add += wsum[0];
    if (w > 1) add += wsum[1];
    if (w > 2) add += wsum[2];
    v += add;
    if (tid == 255) tot = v;
    __syncthreads();
    *total = tot;
    __syncthreads();
    return v;
}

__global__ __launch_bounds__(256) void k_scanA(const int* __restrict__ cnt, int n,
                                               int* __restrict__ bsums) {
    int tid = threadIdx.x;
    int idx = blockIdx.x * 1024 + tid * 4;
    int s = 0;
#pragma unroll
    for (int k = 0; k < 4; ++k) { int i = idx + k; if (i < n) s += cnt[i]; }
#pragma unroll
    for (int o = 32; o > 0; o >>= 1) s += __shfl_xor(s, o, 64);
    __shared__ int ws[4];
    if ((tid & 63) == 0) ws[tid >> 6] = s;
    __syncthreads();
    if (tid == 0) bsums[blockIdx.x] = ws[0] + ws[1] + ws[2] + ws[3];
}

__global__ __launch_bounds__(256) void k_scanB(int* __restrict__ bsums, int nb,
                                               int* __restrict__ rowptr, int N) {
    int tid = threadIdx.x;
    __shared__ int sh_carry;
    if (tid == 0) sh_carry = 0;
    __syncthreads();
    int niter = (nb + 255) / 256;
    for (int it = 0; it < niter; ++it) {
        int i = it * 256 + tid;
        int v = (i < nb) ? bsums[i] : 0;
        int tot;
        int inc = block_incl_scan(v, tid, &tot);
        int carry = sh_carry;
        if (i < nb) bsums[i] = carry + inc - v;
        __syncthreads();
        if (tid == 0) sh_carry = carry + tot;
        __syncthreads();
    }
    if (tid == 0) rowptr[N] = sh_carry;
}

__global__ __launch_bounds__(256) void k_scanC(int* __restrict__ cnt_rowptr, int n,
                                               const int* __restrict__ bsums,
                                               int* __restrict__ cursor) {
    int tid = threadIdx.x;
    int idx = blockIdx.x * 1024 + tid * 4;
    int v[4]; int s = 0;
#pragma unroll
    for (int k = 0; k < 4; ++k) { int i = idx + k; v[k] = (i < n) ? cnt_rowptr[i] : 0; s += v[k]; }
    int tot;
    int inc = block_incl_scan(s, tid, &tot);
    int off = bsums[blockIdx.x] + inc - s;
#pragma unroll
    for (int k = 0; k < 4; ++k) {
        int i = idx + k;
        if (i < n) { cnt_rowptr[i] = off; cursor[i] = off; off += v[k]; }
    }
}

__global__ void k_fill(const int* __restrict__ ei, const int* __restrict__ flag, int E,
                       int* __restrict__ cursor, int* __restrict__ csr) {
    int e = blockIdx.x * blockDim.x + threadIdx.x;
    if (e >= E) return;
    int f = *flag, s, d;
    load_edge(ei, E, e, f, s, d);
    int pos = atomicAdd(&cursor[d], 1);
    csr[pos] = s;
}

// ---------------------------------------------------------------------------
__global__ void k_gather1(const float* __restrict__ x, const int* __restrict__ rowptr,
                          const int* __restrict__ csr, float* __restrict__ agg1, int n) {
    int i = blockIdx.x * blockDim.x + threadIdx.x;
    if (i >= n) return;
    int r0 = rowptr[i], r1 = rowptr[i + 1];
    float s0 = 0.f, s1 = 0.f;
    for (int j = r0; j < r1; ++j) {
        int s = csr[j];
        s0 += x[2 * s]; s1 += x[2 * s + 1];
    }
    float inv = 1.f / fmaxf((float)(r1 - r0), 1.f);
    agg1[2 * i] = s0 * inv;
    agg1[2 * i + 1] = s1 * inv;
}

// ---------------------------------------------------------------------------
// Layer-1 dense (K=2): h1 = agg1@W1l + b1 + x@W1r -> bf16 store.
// BN stats accumulated on the TRUNCATED value so BN is self-consistent with
// what downstream kernels read.
__global__ __launch_bounds__(256) void k_dense1(
    const float* __restrict__ x, const float* __restrict__ agg1,
    const float* __restrict__ W1l, const float* __restrict__ b1,
    const float* __restrict__ W1r,
    unsigned short* __restrict__ h1b, float* __restrict__ stats, int n) {
    int tid = threadIdx.x, c = tid & 63, w = tid >> 6;
    float wl0 = W1l[c], wl1 = W1l[64 + c];
    float wr0 = W1r[c], wr1 = W1r[64 + c];
    float bb = b1[c];
    float ls = 0.f, lq = 0.f;
    for (int i = blockIdx.x * 4 + w; i < n; i += gridDim.x * 4) {
        float a0 = agg1[2 * i], a1 = agg1[2 * i + 1];
        float x0 = x[2 * i], x1v = x[2 * i + 1];
        float h = fmaf(a0, wl0, fmaf(a1, wl1, fmaf(x0, wr0, fmaf(x1v, wr1, bb))));
        unsigned short hb = f2bf(h);
        h1b[(size_t)i * 64 + c] = hb;
        float hf = bf2f(hb);
        ls += hf; lq += hf * hf;
    }
    __shared__ float red[256];
    red[tid] = ls; __syncthreads();
    if (tid < 64) atomicAdd(&stats[tid], red[tid] + red[tid + 64] + red[tid + 128] + red[tid + 192]);
    __syncthreads();
    red[tid] = lq; __syncthreads();
    if (tid < 64) atomicAdd(&stats[64 + tid], red[tid] + red[tid + 64] + red[tid + 128] + red[tid + 192]);
}

// ---------------------------------------------------------------------------
__global__ void k_bnfin(const float* __restrict__ stats, const float* __restrict__ g,
                        const float* __restrict__ be, float* __restrict__ coef, float invN) {
    int c = threadIdx.x;
    float m = stats[c] * invN;
    float var = stats[64 + c] * invN - m * m;
    float a = g[c] * rsqrtf(var + EPS);
    coef[c] = a;
    coef[64 + c] = be[c] - m * a;
}

// ---------------------------------------------------------------------------
// Layer-2 gather: agg2[i,c] = mean_j relu(bn1(h1[src_j,c])), bf16 in/out.
__global__ __launch_bounds__(256) void k_gather2(
    const unsigned short* __restrict__ h1b, const int* __restrict__ rowptr,
    const int* __restrict__ csr, const float* __restrict__ coef1,
    unsigned short* __restrict__ agg2b, int n) {
    int tid = threadIdx.x, c = tid & 63, w = tid >> 6;
    int i = blockIdx.x * 4 + w;
    if (i >= n) return;
    float a1 = coef1[c], b1 = coef1[64 + c];
    int r0 = rowptr[i], r1 = rowptr[i + 1];
    float s = 0.f;
    int j = r0;
    for (; j + 1 < r1; j += 2) {
        int s0 = csr[j], s1 = csr[j + 1];
        float v0 = bf2f(h1b[(size_t)s0 * 64 + c]);
        float v1 = bf2f(h1b[(size_t)s1 * 64 + c]);
        s += fmaxf(0.f, fmaf(v0, a1, b1)) + fmaxf(0.f, fmaf(v1, a1, b1));
    }
    if (j < r1) {
        float v0 = bf2f(h1b[(size_t)csr[j] * 64 + c]);
        s += fmaxf(0.f, fmaf(v0, a1, b1));
    }
    float inv = 1.f / fmaxf((float)(r1 - r0), 1.f);
    agg2b[(size_t)i * 64 + c] = f2bf(s * inv);
}

// ---------------------------------------------------------------------------
// Layer-2 dense via MFMA, bf16 operands end-to-end.
// A = [agg2 | relu(bn1(h1))] (K=128), W = [W2l; W2r] staged in LDS as
// per-lane fragments (16 KB). Register double-buffered A prefetch.
__global__ __launch_bounds__(256) void k_dense2_mfma(
    const unsigned short* __restrict__ agg2b, const unsigned short* __restrict__ h1b,
    const float* __restrict__ coef1,
    const float* __restrict__ W2l, const float* __restrict__ b2,
    const float* __restrict__ W2r,
    unsigned short* __restrict__ h2b, float* __restrict__ stats, int n) {
    __shared__ unsigned short lds_w[16 * 64 * 8];  // [frag=ks*4+cs][lane][j]
    int tid = threadIdx.x;
    int w = tid >> 6;
    int l = tid & 63;
    int ln = l & 15, kg = l >> 4;

    // Stage W fragments: coalesced global reads, scattered 2B LDS writes.
    // k: 0..63 -> W2l, 64..127 -> W2r. frag = (k>>5)*4 + (c>>4);
    // lane = ((k>>3)&3)*16 + (c&15); j = k&7.
    for (int idx = tid; idx < 4096; idx += 256) {
        int k = idx >> 6, c = idx & 63;
        unsigned short wl = f2bf(W2l[idx]);
        unsigned short wr = f2bf(W2r[idx]);
        int lane = ((k >> 3) & 3) * 16 + (c & 15);
        int slotl = (((k >> 5) * 4 + (c >> 4)) * 64 + lane) * 8 + (k & 7);
        int slotr = ((((k + 64) >> 5) * 4 + (c >> 4)) * 64 + lane) * 8 + (k & 7);
        lds_w[slotl] = wl;
        lds_w[slotr] = wr;
    }
    __syncthreads();

    float bb[4];
#pragma unroll
    for (int cs = 0; cs < 4; ++cs) bb[cs] = b2[cs * 16 + ln];

    // BN1 coefs for this lane's k-slice (k = kg*8+j and 32+kg*8+j)
    float c1a[16], c1b[16];
#pragma unroll
    for (int j = 0; j < 8; ++j) {
        c1a[j]     = coef1[kg * 8 + j];       c1b[j]     = coef1[64 + kg * 8 + j];
        c1a[8 + j] = coef1[32 + kg * 8 + j];  c1b[8 + j] = coef1[96 + kg * 8 + j];
    }

    float ls[4] = {0.f, 0.f, 0.f, 0.f};
    float lq[4] = {0.f, 0.f, 0.f, 0.f};

    const bf16x8* wfrag = (const bf16x8*)lds_w;
    int nt = (n + 15) >> 4;
    int stride = gridDim.x * 4;

#define LOADA(T, A)                                                          \
    {                                                                        \
        int i0_ = (T) << 4;                                                  \
        int row_ = i0_ + ln;                                                 \
        int rr_ = (row_ < n) ? row_ : (n - 1);                               \
        const unsigned short* ar_ = agg2b + (size_t)rr_ * 64 + kg * 8;       \
        const unsigned short* xr_ = h1b + (size_t)rr_ * 64 + kg * 8;         \
        A##0 = *(const bf16x8*)ar_;                                          \
        A##1 = *(const bf16x8*)(ar_ + 32);                                   \
        A##2 = *(const bf16x8*)xr_;                                          \
        A##3 = *(const bf16x8*)(xr_ + 32);                                   \
    }

#define PROCESS(T, A)                                                        \
    {                                                                        \
        bf16x8 u2_, u3_;                                                     \
        _Pragma("unroll")                                                    \
        for (int j = 0; j < 8; ++j) {                                        \
            float f2_ = bf2f((unsigned short)A##2[j]);                       \
            float f3_ = bf2f((unsigned short)A##3[j]);                       \
            u2_[j] = (short)f2bf(fmaxf(0.f, fmaf(f2_, c1a[j], c1b[j])));     \
            u3_[j] = (short)f2bf(fmaxf(0.f, fmaf(f3_, c1a[8 + j], c1b[8 + j]))); \
        }                                                                    \
        f32x4 acc_[4];                                                       \
        _Pragma("unroll")                                                    \
        for (int cs = 0; cs < 4; ++cs) acc_[cs] = (f32x4){0.f, 0.f, 0.f, 0.f}; \
        _Pragma("unroll")                                                    \
        for (int cs = 0; cs < 4; ++cs) {                                     \
            acc_[cs] = __builtin_amdgcn_mfma_f32_16x16x32_bf16(A##0, wfrag[(0 * 4 + cs) * 64 + l], acc_[cs], 0, 0, 0); \
            acc_[cs] = __builtin_amdgcn_mfma_f32_16x16x32_bf16(A##1, wfrag[(1 * 4 + cs) * 64 + l], acc_[cs], 0, 0, 0); \
            acc_[cs] = __builtin_amdgcn_mfma_f32_16x16x32_bf16(u2_,  wfrag[(2 * 4 + cs) * 64 + l], acc_[cs], 0, 0, 0); \
            acc_[cs] = __builtin_amdgcn_mfma_f32_16x16x32_bf16(u3_,  wfrag[(3 * 4 + cs) * 64 + l], acc_[cs], 0, 0, 0); \
        }                                                                    \
        int i0_ = (T) << 4;                                                  \
        _Pragma("unroll")                                                    \
        for (int cs = 0; cs < 4; ++cs) {                                     \
            _Pragma("unroll")                                                \
            for (int r = 0; r < 4; ++r) {                                    \
                int orow_ = i0_ + kg * 4 + r;                                \
                if (orow_ < n) {                                             \
                    float h_ = acc_[cs][r] + bb[cs];                         \
                    unsigned short hb_ = f2bf(h_);                           \
                    h2b[(size_t)orow_ * 64 + cs * 16 + ln] = hb_;            \
                    float hf_ = bf2f(hb_);                                   \
                    ls[cs] += hf_; lq[cs] += hf_ * hf_;                      \
                }                                                            \
            }                                                                \
        }                                                                    \
    }

    bf16x8 P0, P1, P2, P3, Q0, Q1, Q2, Q3;
    int t = blockIdx.x * 4 + w;
    if (t < nt) {
        LOADA(t, P);
        while (t < nt) {
            int t1 = t + stride;
            if (t1 < nt) LOADA(t1, Q);
            PROCESS(t, P);
            int t2 = t1 + stride;
            if (t2 < nt) LOADA(t2, P);
            if (t1 < nt) PROCESS(t1, Q);
            t = t2;
        }
    }
#undef LOADA
#undef PROCESS

#pragma unroll
    for (int cs = 0; cs < 4; ++cs) {
        float s = ls[cs], q = lq[cs];
        s += __shfl_xor(s, 16, 64); s += __shfl_xor(s, 32, 64);
        q += __shfl_xor(q, 16, 64); q += __shfl_xor(q, 32, 64);
        if (kg == 0) {
            atomicAdd(&stats[cs * 16 + ln], s);
            atomicAdd(&stats[64 + cs * 16 + ln], q);
        }
    }
}

// ---------------------------------------------------------------------------
// Finalize layer 2 + layer-3 projections, never materializing x2:
// x2 = relu(bn2(h2)) + relu(bn1(h1)); t = x2.W3l; v = x2.W3r
__global__ __launch_bounds__(256) void k_finalize(
    const unsigned short* __restrict__ h2b, const unsigned short* __restrict__ h1b,
    const float* __restrict__ coef1, const float* __restrict__ coef2,
    const float* __restrict__ W3l, const float* __restrict__ W3r,
    float* __restrict__ tb, float* __restrict__ vb, int n) {
    int tid = threadIdx.x, c = tid & 63, w = tid >> 6;
    int i = blockIdx.x * 4 + w;
    if (i >= n) return;
    float a1 = coef1[c], b1 = coef1[64 + c];
    float a2 = coef2[c], b2 = coef2[64 + c];
    float wl = W3l[c], wr = W3r[c];
    float h1v = bf2f(h1b[(size_t)i * 64 + c]);
    float h2v = bf2f(h2b[(size_t)i * 64 + c]);
    float x1v = fmaxf(0.f, fmaf(h1v, a1, b1));
    float x2v = fmaxf(0.f, fmaf(h2v, a2, b2)) + x1v;
    float t = x2v * wl, v = x2v * wr;
#pragma unroll
    for (int o = 32; o > 0; o >>= 1) {
        t += __shfl_xor(t, o, 64);
        v += __shfl_xor(v, o, 64);
    }
    if (c == 0) { tb[i] = t; vb[i] = v; }
}

// ---------------------------------------------------------------------------
__global__ void k_gather3(const float* __restrict__ tb, const float* __restrict__ vb,
                          const int* __restrict__ rowptr, const int* __restrict__ csr,
                          const float* __restrict__ b3, float* __restrict__ out, int n) {
    int i = blockIdx.x * blockDim.x + threadIdx.x;
    if (i >= n) return;
    int r0 = rowptr[i], r1 = rowptr[i + 1];
    float s = 0.f;
    for (int j = r0; j < r1; ++j) s += tb[csr[j]];
    float inv = 1.f / fmaxf((float)(r1 - r0), 1.f);
    out[i] = fmaf(s, inv, b3[0] + vb[i]);
}

// ---------------------------------------------------------------------------
// Workspace (4B units, N=500k, E=1.25M; cap = 256 MiB = 67,108,864 units):
//   h1b   32N = 16,000,000 (bf16 64/row)
//   agg2b 32N = 16,000,000
//   h2b   32N = 16,000,000
//   R      2N =  1,000,000  TIME-SHARED: cursor[N+1] -> agg1[2N] -> tb[N]+vb[N]
//   rowptr N+1, csr E, bsums 2048, stats/coef 512, flag 64
// total ~50.75M units = 203 MB (53 MB slack)
extern "C" void kernel_launch(void* const* d_in, const int* in_sizes, int n_in,
                              void* d_out, int out_size, void* d_ws, size_t ws_size,
                              hipStream_t stream) {
    const float* x   = (const float*)d_in[0];
    const int*   ei  = (const int*)d_in[1];
    const float* W1l = (const float*)d_in[2];
    const float* b1  = (const float*)d_in[3];
    const float* W1r = (const float*)d_in[4];
    const float* g1  = (const float*)d_in[5];
    const float* be1 = (const float*)d_in[6];
    const float* W2l = (const float*)d_in[7];
    const float* b2  = (const float*)d_in[8];
    const float* W2r = (const float*)d_in[9];
    const float* g2  = (const float*)d_in[10];
    const float* be2 = (const float*)d_in[11];
    const float* W3l = (const float*)d_in[12];
    const float* b3  = (const float*)d_in[13];
    const float* W3r = (const float*)d_in[14];

    int N = in_sizes[0] / 2;
    int E = in_sizes[1] / 2;

    float* ws   = (float*)d_ws;
    size_t nn   = (size_t)N;
    unsigned short* h1b   = (unsigned short*)ws;             // 32N units
    unsigned short* agg2b = (unsigned short*)(ws + 32 * nn); // 32N units
    unsigned short* h2b   = (unsigned short*)(ws + 64 * nn); // 32N units
    float* R     = ws + 96 * nn;           // 2N   time-shared region
    int*   cursor = (int*)R;               //   phase 1: CSR build (N+1 ints)
    float* agg1   = R;                     //   phase 2: layer-1 agg (2N f32)
    float* tb     = R;                     //   phase 3: layer-3 t (N f32)
    float* vb     = R + nn;                //   phase 3: layer-3 v (N f32)
    int*   rowptr = (int*)(ws + 98 * nn);  // N+1 (doubles as histogram cnt)
    int*   csr    = rowptr + (N + 1);      // E
    int*   bsums  = csr + E;               // 2048
    float* stats  = (float*)(bsums + 2048);// 256: s1,q1 | s2,q2
    float* coef   = stats + 256;           // 256: a1,b1 | a2,b2
    int*   flag   = (int*)(coef + 256);    // 64 (padded)

    hipMemsetAsync(rowptr, 0, (size_t)(N + 1) * sizeof(int), stream);
    hipMemsetAsync(stats, 0, 256 * sizeof(float), stream);

    k_detect<<<1, 1, 0, stream>>>(ei, flag);

    int ge = (E + 255) / 256;
    int nb = (N + 1023) / 1024;
    k_hist<<<ge, 256, 0, stream>>>(ei, flag, E, rowptr);
    k_scanA<<<nb, 256, 0, stream>>>(rowptr, N, bsums);
    k_scanB<<<1, 256, 0, stream>>>(bsums, nb, rowptr, N);
    k_scanC<<<nb, 256, 0, stream>>>(rowptr, N, bsums, cursor);
    k_fill<<<ge, 256, 0, stream>>>(ei, flag, E, cursor, csr);
    // cursor dead; R becomes agg1

    k_gather1<<<(N + 255) / 256, 256, 0, stream>>>(x, rowptr, csr, agg1, N);
    k_dense1<<<1024, 256, 0, stream>>>(x, agg1, W1l, b1, W1r, h1b, stats, N);
    k_bnfin<<<1, 64, 0, stream>>>(stats, g1, be1, coef, 1.0f / (float)N);
    // agg1 dead after dense1

    int gw = (N + 3) / 4;  // wave-per-node kernels
    k_gather2<<<gw, 256, 0, stream>>>(h1b, rowptr, csr, coef, agg2b, N);
    k_dense2_mfma<<<1024, 256, 0, stream>>>(agg2b, h1b, coef, W2l, b2, W2r, h2b, stats + 128, N);
    k_bnfin<<<1, 64, 0, stream>>>(stats + 128, g2, be2, coef + 128, 1.0f / (float)N);

    // R becomes tb/vb
    k_finalize<<<gw, 256, 0, stream>>>(h2b, h1b, coef, coef + 128, W3l, W3r, tb, vb, N);
    k_gather3<<<(N + 255) / 256, 256, 0, stream>>>(tb, vb, rowptr, csr, b3, (float*)d_out, N);
}